// Round 5
// baseline (447.933 us; speedup 1.0000x reference)
//
#include <hip/hip_runtime.h>
#include <math.h>

#define H 1024
#define Nn 1024
#define Bb 64
#define Tt 256
#define BT (Bb * Tt)   // 16384

typedef unsigned short ushort_t;
typedef __attribute__((ext_vector_type(8))) short bf16x8;
typedef __attribute__((ext_vector_type(4))) float f32x4;

// ---------------- helpers ----------------

__device__ __forceinline__ ushort_t f2bf(float x) {
    union { float f; unsigned u; } v; v.f = x;
    unsigned r = v.u + 0x7FFFu + ((v.u >> 16) & 1u);   // RNE
    return (ushort_t)(r >> 16);
}
__device__ __forceinline__ float bf2f(ushort_t h) {
    union { unsigned u; float f; } v; v.u = ((unsigned)h) << 16; return v.f;
}

__device__ __forceinline__ float block_reduce_sum_256(float v) {
    __shared__ float sbuf[4];
    __syncthreads();
    #pragma unroll
    for (int off = 32; off > 0; off >>= 1) v += __shfl_down(v, off, 64);
    int lane = threadIdx.x & 63, w = threadIdx.x >> 6;
    if (lane == 0) sbuf[w] = v;
    __syncthreads();
    if (threadIdx.x == 0) sbuf[0] = sbuf[0] + sbuf[1] + sbuf[2] + sbuf[3];
    __syncthreads();
    return sbuf[0];
}

// ---------------- small kernels ----------------

// h_gate[b,h] = mean_t h_time[b,t,h]; bf16 copy of h_time; init accumulators.  grid(4,64) x 256
__global__ void k_hgate(const float* __restrict__ h_time, float* __restrict__ h_gate,
                        ushort_t* __restrict__ ht_bf16, const float* __restrict__ n2h_b,
                        float* __restrict__ gsum, float* __restrict__ rowsumS,
                        float* __restrict__ bias_h) {
    int b = blockIdx.y;
    int col = blockIdx.x * 256 + threadIdx.x;
    if (b == 0) {   // zero/seed the atomic accumulators (ws is re-poisoned every call)
        gsum[col] = 0.f;
        rowsumS[col] = 0.f;
        bias_h[col] = n2h_b[col];
    }
    float s = 0.f;
    const size_t base = (size_t)b * Tt * H + col;
    for (int t = 0; t < Tt; ++t) {
        float v = h_time[base + (size_t)t * H];
        s += v;
        ht_bf16[base + (size_t)t * H] = f2bf(v);
    }
    h_gate[b * H + col] = s * (1.0f / Tt);
}

// h_mean[h] = mean_b h_gate[b,h].  grid(4) x 256
__global__ void k_hmean(const float* __restrict__ h_gate, float* __restrict__ h_mean) {
    int h = blockIdx.x * 256 + threadIdx.x;
    float s = 0.f;
    for (int b = 0; b < Bb; ++b) s += h_gate[b * H + h];
    h_mean[h] = s * (1.0f / Bb);
}

// E_b[n,:] = bf16(normalize(E_dyn[n,:] + h_mean)).  grid(1024) x 256
__global__ void k_ecur(const float* __restrict__ E_dyn, const float* __restrict__ h_mean,
                       ushort_t* __restrict__ E_b) {
    int n = blockIdx.x;
    float e[4]; float ss = 0.f;
    #pragma unroll
    for (int q = 0; q < 4; ++q) {
        int h = threadIdx.x + 256 * q;
        e[q] = E_dyn[(size_t)n * H + h] + h_mean[h];
        ss += e[q] * e[q];
    }
    float tot = block_reduce_sum_256(ss);
    float scale = 1.0f / fmaxf(sqrtf(tot), 1e-12f);
    #pragma unroll
    for (int q = 0; q < 4; ++q) {
        int h = threadIdx.x + 256 * q;
        E_b[(size_t)n * H + h] = f2bf(e[q] * scale);
    }
}

// fused gate MLP: gelu(h_gate@W1+b1)@W2+b2 -> sigmoid -> atomicAdd into gsum.  grid(64) x 512
__global__ __launch_bounds__(512) void k_gate_fused(
    const float* __restrict__ h_gate, const float* __restrict__ W1, const float* __restrict__ b1,
    const float* __restrict__ W2, const float* __restrict__ b2, float* __restrict__ gsum) {
    __shared__ float sh[H];
    __shared__ float shid[512];
    int b = blockIdx.x, tid = threadIdx.x;
    sh[tid] = h_gate[b * H + tid];
    sh[tid + 512] = h_gate[b * H + tid + 512];
    __syncthreads();
    float acc = b1[tid];
    for (int k = 0; k < H; ++k) acc = fmaf(sh[k], W1[(size_t)k * 512 + tid], acc);
    shid[tid] = 0.5f * acc * (1.0f + erff(acc * 0.70710678118654752f));
    __syncthreads();
    #pragma unroll
    for (int hh = 0; hh < 2; ++hh) {
        int n = hh * 512 + tid;
        float a2 = b2[n];
        for (int k = 0; k < 512; ++k) a2 = fmaf(shid[k], W2[(size_t)k * Nn + n], a2);
        atomicAdd(&gsum[n], 1.0f / (1.0f + expf(-a2)));
    }
}

// prep: z=0: A_mixT hi/lo from S/rowsum/gsum/A_p; z=1: n2h_W^T hi/lo; z=2: h2n_W split hi/lo.
// grid(32,32,3) x 256
__global__ void k_prep(const ushort_t* __restrict__ Sb, const float* __restrict__ A_p,
                       const float* __restrict__ rowsumS, const float* __restrict__ gsum,
                       const float* __restrict__ alpha_raw,
                       const float* __restrict__ n2h_W, const float* __restrict__ h2n_W,
                       ushort_t* __restrict__ AmixT_h, ushort_t* __restrict__ AmixT_l,
                       ushort_t* __restrict__ n2hWT_h, ushort_t* __restrict__ n2hWT_l,
                       ushort_t* __restrict__ h2nW_h, ushort_t* __restrict__ h2nW_l) {
    __shared__ float tile[32][33];
    int z = blockIdx.z;
    int i0 = blockIdx.y * 32, j0 = blockIdx.x * 32;
    int tx = threadIdx.x & 31, ty = threadIdx.x >> 5;
    if (z == 2) {   // elementwise split of h2n_W (row-major, no transpose)
        #pragma unroll
        for (int q = 0; q < 4; ++q) {
            size_t idx = (size_t)(i0 + ty + 8 * q) * Nn + j0 + tx;
            float v = h2n_W[idx];
            ushort_t hh = f2bf(v);
            h2nW_h[idx] = hh;
            h2nW_l[idx] = f2bf(v - bf2f(hh));
        }
        return;
    }
    if (z == 0) {
        float alpha = 1.0f / (1.0f + expf(-alpha_raw[0]));
        #pragma unroll
        for (int q = 0; q < 4; ++q) {
            int i = i0 + ty + 8 * q, j = j0 + tx;
            size_t idx = (size_t)i * Nn + j;
            float s = bf2f(Sb[idx]);
            float ad = 0.5f * s * (1.0f / (rowsumS[i] + 1e-6f) + 1.0f / (rowsumS[j] + 1e-6f));
            tile[ty + 8 * q][tx] = (gsum[i] * (1.0f / Bb)) * fmaf(alpha, A_p[idx], (1.0f - alpha) * ad);
        }
    } else {
        #pragma unroll
        for (int q = 0; q < 4; ++q)
            tile[ty + 8 * q][tx] = n2h_W[(size_t)(i0 + ty + 8 * q) * H + j0 + tx];
    }
    __syncthreads();
    ushort_t* Th = z ? n2hWT_h : AmixT_h;
    ushort_t* Tl = z ? n2hWT_l : AmixT_l;
    #pragma unroll
    for (int q = 0; q < 4; ++q) {
        float v = tile[tx][ty + 8 * q];
        size_t o = (size_t)(j0 + ty + 8 * q) * Nn + i0 + tx;
        ushort_t hh = f2bf(v);
        Th[o] = hh;
        Tl[o] = f2bf(v - bf2f(hh));
    }
}

// ---------------- unified MFMA bf16 GEMM with fused epilogues ----------------
// C_raw[m][n] = A@Bt^T (PASSES=1) or Ah@Bh^T + Ah@Bl^T + Al@Bh^T (PASSES=3)
// MODE 0: 2D grid (blockIdx.y->m, blockIdx.x->n).  MODE 1: 1D grid 1024 w/ XCD swizzle.
// EPI 1: relu -> O1 bf16, atomicAdd row-sums into fout.          (S = relu(E E^T))
// EPI 2: O1/O2 = hi/lo bf16 split; atomicAdd dot(row, fvec) into fout.  (C1T + bias_h)
// EPI 3: O1 = bf16.                                              (C2t)
// EPI 4: fout[m][n] = raw + fvec[n] + SCALE*bf16(hvec[m][n]), fp32.  (y, pre-LN)
template <int PASSES, int MODE, int EPI>
__global__ __launch_bounds__(256) void gemm_bt(
    const ushort_t* __restrict__ Ah, const ushort_t* __restrict__ Al,
    const ushort_t* __restrict__ Bh, const ushort_t* __restrict__ Bl,
    ushort_t* __restrict__ O1, ushort_t* __restrict__ O2,
    float* __restrict__ fout, const float* __restrict__ fvec,
    const ushort_t* __restrict__ hvec,
    int M, int N, int K) {
    constexpr int NST = (PASSES == 3) ? 4 : 2;
    __shared__ ushort_t sStage[NST * 128 * 32];
    ushort_t* sAh = sStage;
    ushort_t* sBh = sStage + 128 * 32;
    ushort_t* sAl = sStage + (NST == 4 ? 2 * 128 * 32 : 0);
    ushort_t* sBl = sStage + (NST == 4 ? 3 * 128 * 32 : 0);
    __shared__ float EsF[(EPI == 4) ? 1 : 4 * 16 * 68];   // chain epilogue buffer

    const int tid = threadIdx.x;
    const int wave = tid >> 6, lane = tid & 63;
    const int quad = lane >> 4, l16 = lane & 15;
    int m0, n0;
    if (MODE == 1) {
        int bx = blockIdx.x, g = bx & 7, s = bx >> 3;   // XCD-aware: A-panel locality per XCD
        m0 = (g * 16 + (s >> 3)) * 128;
        n0 = (s & 7) * 128;
    } else {
        m0 = blockIdx.y * 128; n0 = blockIdx.x * 128;
    }
    const int wm = (wave >> 1) * 64, wn = (wave & 1) * 64;

    f32x4 acc[4][4];
    #pragma unroll
    for (int i = 0; i < 4; ++i)
        #pragma unroll
        for (int j = 0; j < 4; ++j)
            acc[i][j] = (f32x4){0.f, 0.f, 0.f, 0.f};

    for (int k0 = 0; k0 < K; k0 += 32) {
        __syncthreads();
        #pragma unroll
        for (int inst = 0; inst < 2; ++inst) {
            const int cbase = (wave * 2 + inst) * 64;
            const int c = cbase + lane;
            const int row = c >> 2, q = c & 3;
            const size_t offA = (size_t)(m0 + row) * K + k0 + q * 8;
            const size_t offB = (size_t)(n0 + row) * K + k0 + q * 8;
            __builtin_amdgcn_global_load_lds(
                (const __attribute__((address_space(1))) unsigned int*)(Ah + offA),
                (__attribute__((address_space(3))) unsigned int*)&sAh[cbase * 8], 16, 0, 0);
            __builtin_amdgcn_global_load_lds(
                (const __attribute__((address_space(1))) unsigned int*)(Bh + offB),
                (__attribute__((address_space(3))) unsigned int*)&sBh[cbase * 8], 16, 0, 0);
            if constexpr (PASSES == 3) {
                __builtin_amdgcn_global_load_lds(
                    (const __attribute__((address_space(1))) unsigned int*)(Al + offA),
                    (__attribute__((address_space(3))) unsigned int*)&sAl[cbase * 8], 16, 0, 0);
                __builtin_amdgcn_global_load_lds(
                    (const __attribute__((address_space(1))) unsigned int*)(Bl + offB),
                    (__attribute__((address_space(3))) unsigned int*)&sBl[cbase * 8], 16, 0, 0);
            }
        }
        __syncthreads();
        bf16x8 fah[4], fbh[4];
        bf16x8 fal[PASSES == 3 ? 4 : 1], fbl[PASSES == 3 ? 4 : 1];
        #pragma unroll
        for (int i = 0; i < 4; ++i) {
            fah[i] = *(const bf16x8*)&sAh[(wm + i * 16 + l16) * 32 + quad * 8];
            fbh[i] = *(const bf16x8*)&sBh[(wn + i * 16 + l16) * 32 + quad * 8];
            if constexpr (PASSES == 3) {
                fal[i] = *(const bf16x8*)&sAl[(wm + i * 16 + l16) * 32 + quad * 8];
                fbl[i] = *(const bf16x8*)&sBl[(wn + i * 16 + l16) * 32 + quad * 8];
            }
        }
        #pragma unroll
        for (int i = 0; i < 4; ++i)
            #pragma unroll
            for (int j = 0; j < 4; ++j) {
                acc[i][j] = __builtin_amdgcn_mfma_f32_16x16x32_bf16(fah[i], fbh[j], acc[i][j], 0, 0, 0);
                if constexpr (PASSES == 3) {
                    acc[i][j] = __builtin_amdgcn_mfma_f32_16x16x32_bf16(fah[i], fbl[j], acc[i][j], 0, 0, 0);
                    acc[i][j] = __builtin_amdgcn_mfma_f32_16x16x32_bf16(fal[i], fbh[j], acc[i][j], 0, 0, 0);
                }
            }
    }
    __syncthreads();   // all waves done with staging LDS before epilogue reuse/overlay

    // epilogue: per-wave LDS transpose (EPI==4 overlays the dead staging buffer).
    // NOTE: the write->read phases type-pun LDS (float stores read as float4; EPI==4
    // additionally overlays a ushort buffer). __syncthreads() between the phases is
    // REQUIRED: it is the fence that stops the compiler reordering the float4 loads
    // above the float stores (R4 removed it -> garbage output; R2/R3 had it -> passed).
    float* EsW;
    if constexpr (EPI == 4) EsW = (float*)sStage + wave * (16 * 64);
    else                    EsW = EsF + wave * (16 * 68);
    constexpr int ESTR = (EPI == 4) ? 64 : 68;
    const float SC = 1.0009765622f;   // 1 + tanh(1/1024): global attention weight is constant

    #pragma unroll
    for (int i = 0; i < 4; ++i) {
        #pragma unroll
        for (int j = 0; j < 4; ++j)
            #pragma unroll
            for (int r = 0; r < 4; ++r)
                EsW[(quad * 4 + r) * ESTR + j * 16 + l16] = acc[i][j][r];
        __syncthreads();
        #pragma unroll
        for (int it = 0; it < 4; ++it) {
            const int idx = it * 64 + lane;
            const int row = idx >> 4, f4 = idx & 15;
            const int m = m0 + wm + i * 16 + row;
            const int coln = n0 + wn + f4 * 4;
            float4 v = *(const float4*)&EsW[row * ESTR + f4 * 4];
            if constexpr (EPI == 1) {
                v.x = fmaxf(v.x, 0.f); v.y = fmaxf(v.y, 0.f);
                v.z = fmaxf(v.z, 0.f); v.w = fmaxf(v.w, 0.f);
                ushort4 o; o.x = f2bf(v.x); o.y = f2bf(v.y); o.z = f2bf(v.z); o.w = f2bf(v.w);
                *(ushort4*)&O1[(size_t)m * N + coln] = o;
                float p = v.x + v.y + v.z + v.w;
                p += __shfl_xor(p, 1); p += __shfl_xor(p, 2);
                p += __shfl_xor(p, 4); p += __shfl_xor(p, 8);
                if ((lane & 15) == 0) atomicAdd(&fout[m], p);
            } else if constexpr (EPI == 2) {
                ushort4 hq, lq;
                hq.x = f2bf(v.x); lq.x = f2bf(v.x - bf2f(hq.x));
                hq.y = f2bf(v.y); lq.y = f2bf(v.y - bf2f(hq.y));
                hq.z = f2bf(v.z); lq.z = f2bf(v.z - bf2f(hq.z));
                hq.w = f2bf(v.w); lq.w = f2bf(v.w - bf2f(hq.w));
                *(ushort4*)&O1[(size_t)m * N + coln] = hq;
                *(ushort4*)&O2[(size_t)m * N + coln] = lq;
                float4 b4 = *(const float4*)&fvec[coln];
                float p = v.x * b4.x + v.y * b4.y + v.z * b4.z + v.w * b4.w;
                p += __shfl_xor(p, 1); p += __shfl_xor(p, 2);
                p += __shfl_xor(p, 4); p += __shfl_xor(p, 8);
                if ((lane & 15) == 0) atomicAdd(&fout[m], p);
            } else if constexpr (EPI == 3) {
                ushort4 o; o.x = f2bf(v.x); o.y = f2bf(v.y); o.z = f2bf(v.z); o.w = f2bf(v.w);
                *(ushort4*)&O1[(size_t)m * N + coln] = o;
            } else {   // EPI == 4: y = msg + bias + scale*h_time (bf16 source), fp32 out
                float4 b4 = *(const float4*)&fvec[coln];
                ushort4 h4 = *(const ushort4*)&hvec[(size_t)m * N + coln];
                float4 y;
                y.x = v.x + b4.x + SC * bf2f(h4.x);
                y.y = v.y + b4.y + SC * bf2f(h4.y);
                y.z = v.z + b4.z + SC * bf2f(h4.z);
                y.w = v.w + b4.w + SC * bf2f(h4.w);
                *(float4*)&fout[(size_t)m * N + coln] = y;
            }
        }
        __syncthreads();
    }
}

// ---------------- final LayerNorm, in-place on out (y already assembled).  grid(16384) x 256
__global__ void k_final_ln(const float* __restrict__ ln_w, const float* __restrict__ ln_b,
                           float* __restrict__ out) {
    size_t base = (size_t)blockIdx.x * H;
    int t4 = threadIdx.x * 4;
    float4 y4 = *(const float4*)&out[base + t4];
    float mu = block_reduce_sum_256(y4.x + y4.y + y4.z + y4.w) * (1.0f / H);
    float dx = y4.x - mu, dy = y4.y - mu, dz = y4.z - mu, dw = y4.w - mu;
    float var = block_reduce_sum_256(dx * dx + dy * dy + dz * dz + dw * dw) * (1.0f / H);
    float rstd = rsqrtf(var + 1e-5f);
    float4 w4 = *(const float4*)&ln_w[t4];
    float4 b4 = *(const float4*)&ln_b[t4];
    float4 o;
    o.x = fmaf(dx * rstd, w4.x, b4.x);
    o.y = fmaf(dy * rstd, w4.y, b4.y);
    o.z = fmaf(dz * rstd, w4.z, b4.z);
    o.w = fmaf(dw * rstd, w4.w, b4.w);
    *(float4*)&out[base + t4] = o;
}

// ---------------- launch ----------------

extern "C" void kernel_launch(void* const* d_in, const int* in_sizes, int n_in,
                              void* d_out, int out_size, void* d_ws, size_t ws_size,
                              hipStream_t stream) {
    const float* h_time    = (const float*)d_in[0];
    const float* A_p       = (const float*)d_in[1];
    const float* E_dyn     = (const float*)d_in[2];
    const float* alpha_raw = (const float*)d_in[3];
    // d_in[4] = tau_raw: unused (softmax over axis 0 => node_attn.mean(0) == 1/N exactly)
    const float* gW1   = (const float*)d_in[5];
    const float* gb1   = (const float*)d_in[6];
    const float* gW2   = (const float*)d_in[7];
    const float* gb2   = (const float*)d_in[8];
    const float* h2n_W = (const float*)d_in[9];
    const float* h2n_b = (const float*)d_in[10];
    const float* n2h_W = (const float*)d_in[11];
    const float* n2h_b = (const float*)d_in[12];
    const float* ln_w  = (const float*)d_in[13];
    const float* ln_b  = (const float*)d_in[14];
    float* out = (float*)d_out;

    float* ws = (float*)d_ws;
    float* h_gate  = ws;  ws += Bb * H;
    float* h_mean  = ws;  ws += H;
    float* gsum    = ws;  ws += Nn;
    float* rowsumS = ws;  ws += Nn;
    float* bias_h  = ws;  ws += H;
    ws += 256;   // alignment pad
    ushort_t* E_b     = (ushort_t*)ws;  ws += (Nn * H) / 2;
    ushort_t* Sb      = (ushort_t*)ws;  ws += (Nn * Nn) / 2;
    ushort_t* AmixT_h = (ushort_t*)ws;  ws += (Nn * Nn) / 2;
    ushort_t* AmixT_l = (ushort_t*)ws;  ws += (Nn * Nn) / 2;
    ushort_t* n2hWT_h = (ushort_t*)ws;  ws += (Nn * H) / 2;
    ushort_t* n2hWT_l = (ushort_t*)ws;  ws += (Nn * H) / 2;
    ushort_t* h2nW_h  = (ushort_t*)ws;  ws += (H * Nn) / 2;
    ushort_t* h2nW_l  = (ushort_t*)ws;  ws += (H * Nn) / 2;
    ushort_t* C1Th    = (ushort_t*)ws;  ws += (H * Nn) / 2;
    ushort_t* C1Tl    = (ushort_t*)ws;  ws += (H * Nn) / 2;
    ushort_t* C2t     = (ushort_t*)ws;  ws += (H * H) / 2;
    ushort_t* ht      = (ushort_t*)ws;  ws += ((size_t)BT * H) / 2;

    // 1: means + bf16 h_time + accumulator init
    k_hgate<<<dim3(4, 64), 256, 0, stream>>>(h_time, h_gate, ht, n2h_b, gsum, rowsumS, bias_h);
    // 2: h_mean
    k_hmean<<<4, 256, 0, stream>>>(h_gate, h_mean);
    // 3: E_cur bf16
    k_ecur<<<1024, 256, 0, stream>>>(E_dyn, h_mean, E_b);
    // 4: gate MLP -> gsum (atomic)
    k_gate_fused<<<64, 512, 0, stream>>>(h_gate, gW1, gb1, gW2, gb2, gsum);
    // 5: S = relu(E E^T) bf16 + row sums (fused epilogue)
    gemm_bt<1, 0, 1><<<dim3(8, 8), 256, 0, stream>>>(
        E_b, nullptr, E_b, nullptr, Sb, nullptr, rowsumS, nullptr, nullptr, Nn, Nn, H);
    // 6: A_mixT hi/lo + n2h_W^T hi/lo + h2n_W hi/lo (one kernel)
    k_prep<<<dim3(32, 32, 3), 256, 0, stream>>>(Sb, A_p, rowsumS, gsum, alpha_raw, n2h_W, h2n_W,
                                                AmixT_h, AmixT_l, n2hWT_h, n2hWT_l, h2nW_h, h2nW_l);
    // 7: C1T = n2h_W^T @ A_mix^T (3-pass split) -> hi/lo + fused bias_h gemv
    gemm_bt<3, 0, 2><<<dim3(8, 8), 256, 0, stream>>>(
        n2hWT_h, n2hWT_l, AmixT_h, AmixT_l, C1Th, C1Tl, bias_h, h2n_b, nullptr, Nn, Nn, Nn);
    // 8: C2t = C1T @ h2n_W^T-form (3-pass split) -> bf16
    gemm_bt<3, 0, 3><<<dim3(8, 8), 256, 0, stream>>>(
        C1Th, C1Tl, h2nW_h, h2nW_l, C2t, nullptr, nullptr, nullptr, nullptr, H, H, Nn);
    // 9: y = ht @ C2t^T + bias_h + SC*ht  -> d_out fp32 (fused epilogue)
    gemm_bt<1, 1, 4><<<1024, 256, 0, stream>>>(
        ht, nullptr, C2t, nullptr, nullptr, nullptr, out, bias_h, ht, BT, H, H);
    // 10: LayerNorm in place
    k_final_ln<<<BT, 256, 0, stream>>>(ln_w, ln_b, out);
}

// Round 6
// 366.245 us; speedup vs baseline: 1.2230x; 1.2230x over previous
//
#include <hip/hip_runtime.h>
#include <math.h>

#define H 1024
#define Nn 1024
#define Bb 64
#define Tt 256
#define BT (Bb * Tt)   // 16384

typedef unsigned short ushort_t;
typedef __attribute__((ext_vector_type(8))) short bf16x8;
typedef __attribute__((ext_vector_type(4))) float f32x4;

// ---------------- helpers ----------------

__device__ __forceinline__ ushort_t f2bf(float x) {
    union { float f; unsigned u; } v; v.f = x;
    unsigned r = v.u + 0x7FFFu + ((v.u >> 16) & 1u);   // RNE
    return (ushort_t)(r >> 16);
}
__device__ __forceinline__ float bf2f(ushort_t h) {
    union { unsigned u; float f; } v; v.u = ((unsigned)h) << 16; return v.f;
}

__device__ __forceinline__ float block_reduce_sum_256(float v) {
    __shared__ float sbuf[4];
    __syncthreads();
    #pragma unroll
    for (int off = 32; off > 0; off >>= 1) v += __shfl_down(v, off, 64);
    int lane = threadIdx.x & 63, w = threadIdx.x >> 6;
    if (lane == 0) sbuf[w] = v;
    __syncthreads();
    if (threadIdx.x == 0) sbuf[0] = sbuf[0] + sbuf[1] + sbuf[2] + sbuf[3];
    __syncthreads();
    return sbuf[0];
}

// ---------------- small kernels ----------------

// h_gate[b,h] = mean_t h_time[b,t,h]; bf16 copy of h_time; init accumulators.  grid(4,64) x 256
__global__ void k_hgate(const float* __restrict__ h_time, float* __restrict__ h_gate,
                        ushort_t* __restrict__ ht_bf16, const float* __restrict__ n2h_b,
                        float* __restrict__ rowsumS, float* __restrict__ bias_h) {
    int b = blockIdx.y;
    int col = blockIdx.x * 256 + threadIdx.x;
    if (b == 0) {   // seed the atomic accumulators (ws is re-poisoned every call)
        rowsumS[col] = 0.f;
        bias_h[col] = n2h_b[col];
    }
    float s = 0.f;
    const size_t base = (size_t)b * Tt * H + col;
    for (int t = 0; t < Tt; ++t) {
        float v = h_time[base + (size_t)t * H];
        s += v;
        ht_bf16[base + (size_t)t * H] = f2bf(v);
    }
    h_gate[b * H + col] = s * (1.0f / Tt);
}

// h_mean[h] = mean_b h_gate[b,h].  grid(4) x 256
__global__ void k_hmean(const float* __restrict__ h_gate, float* __restrict__ h_mean) {
    int h = blockIdx.x * 256 + threadIdx.x;
    float s = 0.f;
    for (int b = 0; b < Bb; ++b) s += h_gate[b * H + h];
    h_mean[h] = s * (1.0f / Bb);
}

// E_b[n,:] = bf16(normalize(E_dyn[n,:] + h_mean)).  grid(1024) x 256
__global__ void k_ecur(const float* __restrict__ E_dyn, const float* __restrict__ h_mean,
                       ushort_t* __restrict__ E_b) {
    int n = blockIdx.x;
    float e[4]; float ss = 0.f;
    #pragma unroll
    for (int q = 0; q < 4; ++q) {
        int h = threadIdx.x + 256 * q;
        e[q] = E_dyn[(size_t)n * H + h] + h_mean[h];
        ss += e[q] * e[q];
    }
    float tot = block_reduce_sum_256(ss);
    float scale = 1.0f / fmaxf(sqrtf(tot), 1e-12f);
    #pragma unroll
    for (int q = 0; q < 4; ++q) {
        int h = threadIdx.x + 256 * q;
        E_b[(size_t)n * H + h] = f2bf(e[q] * scale);
    }
}

// weight prep, 1D grid 3072 x 256:
//  [0,1024):    n2h_W^T hi/lo bf16 (32x32 LDS transpose tiles over 1024x1024)
//  [1024,2048): h2n_W flat hi/lo bf16 split
//  [2048,2560): W1T fp32 = W1^T (1024x512 -> 512x1024)
//  [2560,3072): W2T fp32 = W2^T (512x1024 -> 1024x512)
__global__ void k_prepW(const float* __restrict__ n2h_W, const float* __restrict__ h2n_W,
                        const float* __restrict__ W1, const float* __restrict__ W2,
                        ushort_t* __restrict__ n2hWT_h, ushort_t* __restrict__ n2hWT_l,
                        ushort_t* __restrict__ h2nW_h, ushort_t* __restrict__ h2nW_l,
                        float* __restrict__ W1T, float* __restrict__ W2T) {
    __shared__ float tile[32][33];
    int id = blockIdx.x;
    int tx = threadIdx.x & 31, ty = threadIdx.x >> 5;
    if (id < 1024) {            // n2h_W transpose + split
        int i0 = (id >> 5) * 32, j0 = (id & 31) * 32;
        #pragma unroll
        for (int q = 0; q < 4; ++q)
            tile[ty + 8 * q][tx] = n2h_W[(size_t)(i0 + ty + 8 * q) * H + j0 + tx];
        __syncthreads();
        #pragma unroll
        for (int q = 0; q < 4; ++q) {
            float v = tile[tx][ty + 8 * q];
            size_t o = (size_t)(j0 + ty + 8 * q) * Nn + i0 + tx;
            ushort_t hh = f2bf(v);
            n2hWT_h[o] = hh;
            n2hWT_l[o] = f2bf(v - bf2f(hh));
        }
    } else if (id < 2048) {     // h2n_W flat split
        size_t idx = (size_t)(id - 1024) * 1024 + threadIdx.x * 4;
        float4 v = *(const float4*)&h2n_W[idx];
        float c[4] = {v.x, v.y, v.z, v.w};
        union { ushort_t u[4]; uint2 w; } ph, pl;
        #pragma unroll
        for (int q = 0; q < 4; ++q) {
            ph.u[q] = f2bf(c[q]);
            pl.u[q] = f2bf(c[q] - bf2f(ph.u[q]));
        }
        *(uint2*)&h2nW_h[idx] = ph.w;
        *(uint2*)&h2nW_l[idx] = pl.w;
    } else if (id < 2560) {     // W1T (W1 is 1024x512)
        int t = id - 2048;
        int i0 = (t >> 4) * 32, j0 = (t & 15) * 32;
        #pragma unroll
        for (int q = 0; q < 4; ++q)
            tile[ty + 8 * q][tx] = W1[(size_t)(i0 + ty + 8 * q) * 512 + j0 + tx];
        __syncthreads();
        #pragma unroll
        for (int q = 0; q < 4; ++q)
            W1T[(size_t)(j0 + ty + 8 * q) * 1024 + i0 + tx] = tile[tx][ty + 8 * q];
    } else {                    // W2T (W2 is 512x1024)
        int t = id - 2560;
        int i0 = (t >> 5) * 32, j0 = (t & 31) * 32;
        #pragma unroll
        for (int q = 0; q < 4; ++q)
            tile[ty + 8 * q][tx] = W2[(size_t)(i0 + ty + 8 * q) * 1024 + j0 + tx];
        __syncthreads();
        #pragma unroll
        for (int q = 0; q < 4; ++q)
            W2T[(size_t)(j0 + ty + 8 * q) * 512 + i0 + tx] = tile[tx][ty + 8 * q];
    }
}

// hid[b][j] = gelu(dot(h_gate[b,:], W1T[j,:]) + b1[j]).  grid(8192) x 256, wave per output
__global__ __launch_bounds__(256) void k_mlp1(const float* __restrict__ h_gate,
                                              const float* __restrict__ W1T,
                                              const float* __restrict__ b1,
                                              float* __restrict__ hid) {
    int gid = blockIdx.x * 4 + (threadIdx.x >> 6);   // 0..32767
    int lane = threadIdx.x & 63;
    int b = gid >> 9, j = gid & 511;
    const float* xr = h_gate + b * H;
    const float* wr = W1T + (size_t)j * H;
    float s = 0.f;
    #pragma unroll
    for (int it = 0; it < 4; ++it) {
        int k = it * 256 + lane * 4;
        float4 x4 = *(const float4*)&xr[k];
        float4 w4 = *(const float4*)&wr[k];
        s += x4.x * w4.x + x4.y * w4.y + x4.z * w4.z + x4.w * w4.w;
    }
    #pragma unroll
    for (int off = 32; off > 0; off >>= 1) s += __shfl_down(s, off, 64);
    if (lane == 0) {
        float a = s + b1[j];
        hid[b * 512 + j] = 0.5f * a * (1.0f + erff(a * 0.70710678118654752f));
    }
}

// gmean[n] = mean_b sigmoid(dot(hid[b,:], W2T[n,:]) + b2[n]).  grid(256) x 256, wave per n
__global__ __launch_bounds__(256) void k_mlp2(const float* __restrict__ hid,
                                              const float* __restrict__ W2T,
                                              const float* __restrict__ b2,
                                              float* __restrict__ gmean) {
    int n = blockIdx.x * 4 + (threadIdx.x >> 6);   // 0..1023
    int lane = threadIdx.x & 63;
    const float* wr = W2T + (size_t)n * 512;
    float4 w0 = *(const float4*)&wr[lane * 4];
    float4 w1 = *(const float4*)&wr[256 + lane * 4];
    float bb = b2[n];
    float acc = 0.f;
    for (int b = 0; b < Bb; ++b) {
        const float* xr = hid + b * 512;
        float4 x0 = *(const float4*)&xr[lane * 4];
        float4 x1 = *(const float4*)&xr[256 + lane * 4];
        float s = x0.x * w0.x + x0.y * w0.y + x0.z * w0.z + x0.w * w0.w
                + x1.x * w1.x + x1.y * w1.y + x1.z * w1.z + x1.w * w1.w;
        #pragma unroll
        for (int off = 32; off > 0; off >>= 1) s += __shfl_down(s, off, 64);
        if (lane == 0) acc += 1.0f / (1.0f + expf(-(s + bb)));
    }
    if (lane == 0) gmean[n] = acc * (1.0f / Bb);
}

// A_mix transposed + hi/lo split.  grid(32,32) x 256
__global__ void k_amixT(const ushort_t* __restrict__ Sb, const float* __restrict__ A_p,
                        const float* __restrict__ rowsumS, const float* __restrict__ gmean,
                        const float* __restrict__ alpha_raw,
                        ushort_t* __restrict__ Th, ushort_t* __restrict__ Tl) {
    __shared__ float tile[32][33];
    int i0 = blockIdx.y * 32, j0 = blockIdx.x * 32;
    int tx = threadIdx.x & 31, ty = threadIdx.x >> 5;
    float alpha = 1.0f / (1.0f + expf(-alpha_raw[0]));
    #pragma unroll
    for (int q = 0; q < 4; ++q) {
        int i = i0 + ty + 8 * q, j = j0 + tx;
        size_t idx = (size_t)i * Nn + j;
        float s = bf2f(Sb[idx]);
        float ad = 0.5f * s * (1.0f / (rowsumS[i] + 1e-6f) + 1.0f / (rowsumS[j] + 1e-6f));
        tile[ty + 8 * q][tx] = gmean[i] * fmaf(alpha, A_p[idx], (1.0f - alpha) * ad);
    }
    __syncthreads();
    #pragma unroll
    for (int q = 0; q < 4; ++q) {
        float v = tile[tx][ty + 8 * q];
        size_t o = (size_t)(j0 + ty + 8 * q) * Nn + i0 + tx;
        ushort_t hh = f2bf(v);
        Th[o] = hh;
        Tl[o] = f2bf(v - bf2f(hh));
    }
}

// ---------------- 64x64-tile MFMA GEMM for the 1024^3 chain (grid 16x16 = full machine) ----
// C_raw = A@Bt^T (PASSES=1) or Ah@Bh^T + Ah@Bl^T + Al@Bh^T (PASSES=3).
// EPI 1: relu -> O1 bf16 + atomicAdd row-sums into fout.      (S = relu(E E^T))
// EPI 2: hi/lo bf16 -> O1,O2 + atomicAdd dot(row,fvec)->fout. (C1T + fused bias_h gemv)
// EPI 3: bf16 -> O1.                                          (C2t)
template <int PASSES, int EPI>
__global__ __launch_bounds__(256) void gemm64_bt(
    const ushort_t* __restrict__ Ah, const ushort_t* __restrict__ Al,
    const ushort_t* __restrict__ Bh, const ushort_t* __restrict__ Bl,
    ushort_t* __restrict__ O1, ushort_t* __restrict__ O2,
    float* __restrict__ fout, const float* __restrict__ fvec,
    int M, int N, int K) {
    constexpr int NST = (PASSES == 3) ? 4 : 2;
    __shared__ ushort_t sStage[NST * 64 * 32];
    ushort_t* sAh = sStage;
    ushort_t* sBh = sStage + 64 * 32;
    ushort_t* sAl = sStage + (NST == 4 ? 2 * 64 * 32 : 0);
    ushort_t* sBl = sStage + (NST == 4 ? 3 * 64 * 32 : 0);
    const int tid = threadIdx.x, wave = tid >> 6, lane = tid & 63;
    const int quad = lane >> 4, l16 = lane & 15;
    const int m0 = blockIdx.y * 64, n0 = blockIdx.x * 64;
    const int wm = (wave >> 1) * 32, wn = (wave & 1) * 32;

    f32x4 acc[2][2];
    #pragma unroll
    for (int i = 0; i < 2; ++i)
        #pragma unroll
        for (int j = 0; j < 2; ++j)
            acc[i][j] = (f32x4){0.f, 0.f, 0.f, 0.f};

    for (int k0 = 0; k0 < K; k0 += 32) {
        __syncthreads();
        {   // stage 64x32 per array: 4 KB = 256 lanes x 16 B (wave-uniform base + lane*16)
            const int row = tid >> 2, q = tid & 3;
            const size_t offA = (size_t)(m0 + row) * K + k0 + q * 8;
            const size_t offB = (size_t)(n0 + row) * K + k0 + q * 8;
            __builtin_amdgcn_global_load_lds(
                (const __attribute__((address_space(1))) unsigned int*)(Ah + offA),
                (__attribute__((address_space(3))) unsigned int*)&sAh[tid * 8], 16, 0, 0);
            __builtin_amdgcn_global_load_lds(
                (const __attribute__((address_space(1))) unsigned int*)(Bh + offB),
                (__attribute__((address_space(3))) unsigned int*)&sBh[tid * 8], 16, 0, 0);
            if constexpr (PASSES == 3) {
                __builtin_amdgcn_global_load_lds(
                    (const __attribute__((address_space(1))) unsigned int*)(Al + offA),
                    (__attribute__((address_space(3))) unsigned int*)&sAl[tid * 8], 16, 0, 0);
                __builtin_amdgcn_global_load_lds(
                    (const __attribute__((address_space(1))) unsigned int*)(Bl + offB),
                    (__attribute__((address_space(3))) unsigned int*)&sBl[tid * 8], 16, 0, 0);
            }
        }
        __syncthreads();
        bf16x8 fah[2], fbh[2];
        bf16x8 fal[PASSES == 3 ? 2 : 1], fbl[PASSES == 3 ? 2 : 1];
        #pragma unroll
        for (int i = 0; i < 2; ++i) {
            fah[i] = *(const bf16x8*)&sAh[(wm + i * 16 + l16) * 32 + quad * 8];
            fbh[i] = *(const bf16x8*)&sBh[(wn + i * 16 + l16) * 32 + quad * 8];
            if constexpr (PASSES == 3) {
                fal[i] = *(const bf16x8*)&sAl[(wm + i * 16 + l16) * 32 + quad * 8];
                fbl[i] = *(const bf16x8*)&sBl[(wn + i * 16 + l16) * 32 + quad * 8];
            }
        }
        #pragma unroll
        for (int i = 0; i < 2; ++i)
            #pragma unroll
            for (int j = 0; j < 2; ++j) {
                acc[i][j] = __builtin_amdgcn_mfma_f32_16x16x32_bf16(fah[i], fbh[j], acc[i][j], 0, 0, 0);
                if constexpr (PASSES == 3) {
                    acc[i][j] = __builtin_amdgcn_mfma_f32_16x16x32_bf16(fah[i], fbl[j], acc[i][j], 0, 0, 0);
                    acc[i][j] = __builtin_amdgcn_mfma_f32_16x16x32_bf16(fal[i], fbh[j], acc[i][j], 0, 0, 0);
                }
            }
    }

    // direct-from-register epilogue (no LDS round-trip; outputs are small/L2-resident).
    // element (i,j,r): row = m0+wm+i*16+quad*4+r, col = n0+wn+j*16+l16.
    float fv[2];
    if constexpr (EPI == 2) {
        #pragma unroll
        for (int j = 0; j < 2; ++j) fv[j] = fvec[n0 + wn + j * 16 + l16];
    }
    #pragma unroll
    for (int i = 0; i < 2; ++i)
        #pragma unroll
        for (int r = 0; r < 4; ++r) {
            const int m = m0 + wm + i * 16 + quad * 4 + r;
            float rowacc = 0.f;
            #pragma unroll
            for (int j = 0; j < 2; ++j) {
                const size_t o = (size_t)m * N + n0 + wn + j * 16 + l16;
                float v = acc[i][j][r];
                if constexpr (EPI == 1) {
                    v = fmaxf(v, 0.f);
                    O1[o] = f2bf(v);
                    rowacc += v;
                } else if constexpr (EPI == 2) {
                    ushort_t hh = f2bf(v);
                    O1[o] = hh;
                    O2[o] = f2bf(v - bf2f(hh));
                    rowacc += v * fv[j];
                } else {
                    O1[o] = f2bf(v);
                }
            }
            if constexpr (EPI == 1 || EPI == 2) {
                rowacc += __shfl_xor(rowacc, 1);
                rowacc += __shfl_xor(rowacc, 2);
                rowacc += __shfl_xor(rowacc, 4);
                rowacc += __shfl_xor(rowacc, 8);
                if (l16 == 0) atomicAdd(&fout[m], rowacc);
            }
        }
}

// ---------------- 128x128 MFMA GEMM, fused y-epilogue (unchanged from R5/verified) -------
// y[m][n] = (ht @ C2t^T)[m][n] + bias[n] + SC*bf16(ht[m][n]), fp32 -> fout.  1D grid 1024.
__global__ __launch_bounds__(256) void gemm_big(
    const ushort_t* __restrict__ A, const ushort_t* __restrict__ Bt,
    float* __restrict__ fout, const float* __restrict__ fvec,
    int M, int N, int K) {
    __shared__ ushort_t sStage[2 * 128 * 32];
    ushort_t* sAh = sStage;
    ushort_t* sBh = sStage + 128 * 32;

    const int tid = threadIdx.x;
    const int wave = tid >> 6, lane = tid & 63;
    const int quad = lane >> 4, l16 = lane & 15;
    int bx = blockIdx.x, g = bx & 7, s = bx >> 3;   // XCD-aware: A-panel locality per XCD
    const int m0 = (g * 16 + (s >> 3)) * 128;
    const int n0 = (s & 7) * 128;
    const int wm = (wave >> 1) * 64, wn = (wave & 1) * 64;

    f32x4 acc[4][4];
    #pragma unroll
    for (int i = 0; i < 4; ++i)
        #pragma unroll
        for (int j = 0; j < 4; ++j)
            acc[i][j] = (f32x4){0.f, 0.f, 0.f, 0.f};

    for (int k0 = 0; k0 < K; k0 += 32) {
        __syncthreads();
        #pragma unroll
        for (int inst = 0; inst < 2; ++inst) {
            const int cbase = (wave * 2 + inst) * 64;
            const int c = cbase + lane;
            const int row = c >> 2, q = c & 3;
            const size_t offA = (size_t)(m0 + row) * K + k0 + q * 8;
            const size_t offB = (size_t)(n0 + row) * K + k0 + q * 8;
            __builtin_amdgcn_global_load_lds(
                (const __attribute__((address_space(1))) unsigned int*)(A + offA),
                (__attribute__((address_space(3))) unsigned int*)&sAh[cbase * 8], 16, 0, 0);
            __builtin_amdgcn_global_load_lds(
                (const __attribute__((address_space(1))) unsigned int*)(Bt + offB),
                (__attribute__((address_space(3))) unsigned int*)&sBh[cbase * 8], 16, 0, 0);
        }
        __syncthreads();
        bf16x8 fah[4], fbh[4];
        #pragma unroll
        for (int i = 0; i < 4; ++i) {
            fah[i] = *(const bf16x8*)&sAh[(wm + i * 16 + l16) * 32 + quad * 8];
            fbh[i] = *(const bf16x8*)&sBh[(wn + i * 16 + l16) * 32 + quad * 8];
        }
        #pragma unroll
        for (int i = 0; i < 4; ++i)
            #pragma unroll
            for (int j = 0; j < 4; ++j)
                acc[i][j] = __builtin_amdgcn_mfma_f32_16x16x32_bf16(fah[i], fbh[j], acc[i][j], 0, 0, 0);
    }
    __syncthreads();   // staging dead; epilogue overlays it

    // Epilogue: per-wave LDS transpose in the dead staging buffer -> coalesced float4 IO.
    // __syncthreads() between write/read phases is REQUIRED (type-punned LDS; R4 lesson).
    float* EsW = (float*)sStage + wave * (16 * 64);
    const float SC = 1.0009765622f;   // 1 + tanh(1/1024): attention branch is this constant

    #pragma unroll
    for (int i = 0; i < 4; ++i) {
        #pragma unroll
        for (int j = 0; j < 4; ++j)
            #pragma unroll
            for (int r = 0; r < 4; ++r)
                EsW[(quad * 4 + r) * 64 + j * 16 + l16] = acc[i][j][r];
        __syncthreads();
        #pragma unroll
        for (int it = 0; it < 4; ++it) {
            const int idx = it * 64 + lane;
            const int row = idx >> 4, f4 = idx & 15;
            const int m = m0 + wm + i * 16 + row;
            const int coln = n0 + wn + f4 * 4;
            float4 v = *(const float4*)&EsW[row * 64 + f4 * 4];
            float4 b4 = *(const float4*)&fvec[coln];
            ushort4 h4 = *(const ushort4*)&A[(size_t)m * N + coln];
            float4 y;
            y.x = v.x + b4.x + SC * bf2f(h4.x);
            y.y = v.y + b4.y + SC * bf2f(h4.y);
            y.z = v.z + b4.z + SC * bf2f(h4.z);
            y.w = v.w + b4.w + SC * bf2f(h4.w);
            *(float4*)&fout[(size_t)m * N + coln] = y;
        }
        __syncthreads();
    }
}

// ---------------- final LayerNorm, in-place on out.  grid(16384) x 256
__global__ void k_final_ln(const float* __restrict__ ln_w, const float* __restrict__ ln_b,
                           float* __restrict__ out) {
    size_t base = (size_t)blockIdx.x * H;
    int t4 = threadIdx.x * 4;
    float4 y4 = *(const float4*)&out[base + t4];
    float mu = block_reduce_sum_256(y4.x + y4.y + y4.z + y4.w) * (1.0f / H);
    float dx = y4.x - mu, dy = y4.y - mu, dz = y4.z - mu, dw = y4.w - mu;
    float var = block_reduce_sum_256(dx * dx + dy * dy + dz * dz + dw * dw) * (1.0f / H);
    float rstd = rsqrtf(var + 1e-5f);
    float4 w4 = *(const float4*)&ln_w[t4];
    float4 b4 = *(const float4*)&ln_b[t4];
    float4 o;
    o.x = fmaf(dx * rstd, w4.x, b4.x);
    o.y = fmaf(dy * rstd, w4.y, b4.y);
    o.z = fmaf(dz * rstd, w4.z, b4.z);
    o.w = fmaf(dw * rstd, w4.w, b4.w);
    *(float4*)&out[base + t4] = o;
}

// ---------------- launch ----------------

extern "C" void kernel_launch(void* const* d_in, const int* in_sizes, int n_in,
                              void* d_out, int out_size, void* d_ws, size_t ws_size,
                              hipStream_t stream) {
    const float* h_time    = (const float*)d_in[0];
    const float* A_p       = (const float*)d_in[1];
    const float* E_dyn     = (const float*)d_in[2];
    const float* alpha_raw = (const float*)d_in[3];
    // d_in[4] = tau_raw: unused (softmax over axis 0 => node_attn.mean(0) == 1/N exactly)
    const float* gW1   = (const float*)d_in[5];
    const float* gb1   = (const float*)d_in[6];
    const float* gW2   = (const float*)d_in[7];
    const float* gb2   = (const float*)d_in[8];
    const float* h2n_W = (const float*)d_in[9];
    const float* h2n_b = (const float*)d_in[10];
    const float* n2h_W = (const float*)d_in[11];
    const float* n2h_b = (const float*)d_in[12];
    const float* ln_w  = (const float*)d_in[13];
    const float* ln_b  = (const float*)d_in[14];
    float* out = (float*)d_out;

    float* ws = (float*)d_ws;
    float* h_gate  = ws;  ws += Bb * H;
    float* h_mean  = ws;  ws += H;
    float* rowsumS = ws;  ws += Nn;
    float* bias_h  = ws;  ws += H;
    float* hid     = ws;  ws += Bb * 512;
    float* gmean   = ws;  ws += Nn;
    float* W1T     = ws;  ws += 512 * H;
    float* W2T     = ws;  ws += H * 512;
    ws += 256;   // alignment pad
    ushort_t* E_b     = (ushort_t*)ws;  ws += (Nn * H) / 2;
    ushort_t* Sb      = (ushort_t*)ws;  ws += (Nn * Nn) / 2;
    ushort_t* AmixT_h = (ushort_t*)ws;  ws += (Nn * Nn) / 2;
    ushort_t* AmixT_l = (ushort_t*)ws;  ws += (Nn * Nn) / 2;
    ushort_t* n2hWT_h = (ushort_t*)ws;  ws += (Nn * H) / 2;
    ushort_t* n2hWT_l = (ushort_t*)ws;  ws += (Nn * H) / 2;
    ushort_t* h2nW_h  = (ushort_t*)ws;  ws += (H * Nn) / 2;
    ushort_t* h2nW_l  = (ushort_t*)ws;  ws += (H * Nn) / 2;
    ushort_t* C1Th    = (ushort_t*)ws;  ws += (H * Nn) / 2;
    ushort_t* C1Tl    = (ushort_t*)ws;  ws += (H * Nn) / 2;
    ushort_t* C2t     = (ushort_t*)ws;  ws += (H * H) / 2;
    ushort_t* ht      = (ushort_t*)ws;  ws += ((size_t)BT * H) / 2;

    // 1: means + bf16 h_time + accumulator init
    k_hgate<<<dim3(4, 64), 256, 0, stream>>>(h_time, h_gate, ht, n2h_b, rowsumS, bias_h);
    // 2: weight prep (transposes + hi/lo splits) — independent of everything above
    k_prepW<<<3072, 256, 0, stream>>>(n2h_W, h2n_W, gW1, gW2,
                                      n2hWT_h, n2hWT_l, h2nW_h, h2nW_l, W1T, W2T);
    // 3: h_mean
    k_hmean<<<4, 256, 0, stream>>>(h_gate, h_mean);
    // 4: E_cur bf16
    k_ecur<<<1024, 256, 0, stream>>>(E_dyn, h_mean, E_b);
    // 5-6: gate MLP (wave-per-output dots on pre-transposed fp32 weights)
    k_mlp1<<<8192, 256, 0, stream>>>(h_gate, W1T, gb1, hid);
    k_mlp2<<<256, 256, 0, stream>>>(hid, W2T, gb2, gmean);
    // 7: S = relu(E E^T) bf16 + row sums (full-machine 64-tile GEMM)
    gemm64_bt<1, 1><<<dim3(16, 16), 256, 0, stream>>>(
        E_b, nullptr, E_b, nullptr, Sb, nullptr, rowsumS, nullptr, Nn, Nn, H);
    // 8: A_mix^T hi/lo
    k_amixT<<<dim3(32, 32), 256, 0, stream>>>(Sb, A_p, rowsumS, gmean, alpha_raw, AmixT_h, AmixT_l);
    // 9: C1T = n2h_W^T @ A_mix^T (3-pass split) -> hi/lo + fused bias_h gemv
    gemm64_bt<3, 2><<<dim3(16, 16), 256, 0, stream>>>(
        n2hWT_h, n2hWT_l, AmixT_h, AmixT_l, C1Th, C1Tl, bias_h, h2n_b, Nn, Nn, Nn);
    // 10: C2t = C1T @ h2n_W (3-pass split) -> bf16   (= C2^T, the big GEMM's B operand)
    gemm64_bt<3, 3><<<dim3(16, 16), 256, 0, stream>>>(
        C1Th, C1Tl, h2nW_h, h2nW_l, C2t, nullptr, nullptr, nullptr, Nn, Nn, Nn);
    // 11: y = ht @ C2t^T + bias_h + SC*ht -> d_out fp32 (fused epilogue)
    gemm_big<<<1024, 256, 0, stream>>>(ht, C2t, out, bias_h, BT, H, H);
    // 12: LayerNorm in place
    k_final_ln<<<BT, 256, 0, stream>>>(ln_w, ln_b, out);
}

// Round 7
// 346.570 us; speedup vs baseline: 1.2925x; 1.0568x over previous
//
#include <hip/hip_runtime.h>
#include <math.h>

#define H 1024
#define Nn 1024
#define Bb 64
#define Tt 256
#define BT (Bb * Tt)   // 16384

typedef unsigned short ushort_t;
typedef __attribute__((ext_vector_type(8))) short bf16x8;
typedef __attribute__((ext_vector_type(4))) float f32x4;

// ---------------- helpers ----------------

__device__ __forceinline__ ushort_t f2bf(float x) {
    union { float f; unsigned u; } v; v.f = x;
    unsigned r = v.u + 0x7FFFu + ((v.u >> 16) & 1u);   // RNE
    return (ushort_t)(r >> 16);
}
__device__ __forceinline__ float bf2f(ushort_t h) {
    union { unsigned u; float f; } v; v.u = ((unsigned)h) << 16; return v.f;
}

__device__ __forceinline__ float block_reduce_sum_256(float v) {
    __shared__ float sbuf[4];
    __syncthreads();
    #pragma unroll
    for (int off = 32; off > 0; off >>= 1) v += __shfl_down(v, off, 64);
    int lane = threadIdx.x & 63, w = threadIdx.x >> 6;
    if (lane == 0) sbuf[w] = v;
    __syncthreads();
    if (threadIdx.x == 0) sbuf[0] = sbuf[0] + sbuf[1] + sbuf[2] + sbuf[3];
    __syncthreads();
    return sbuf[0];
}

// ---------------- stage 1: hgate partials (t-split x8) + bf16 ht + seeds + weight prep ----
// grid 5120 x 256:
//  [0,2048):    b = id>>5, z = (id&31)>>2 (t-chunk of 32), cb = id&3.
//  [2048,3072): n2h_W^T hi/lo bf16 transpose tiles
//  [3072,4096): h2n_W flat hi/lo split
//  [4096,4608): W1T fp32
//  [4608,5120): W2T fp32
__global__ void k_stage1(const float* __restrict__ h_time, float* __restrict__ hg_part,
                         ushort_t* __restrict__ ht_bf16, const float* __restrict__ n2h_b,
                         float* __restrict__ rowsumS, float* __restrict__ bias_h,
                         const float* __restrict__ n2h_W, const float* __restrict__ h2n_W,
                         const float* __restrict__ W1, const float* __restrict__ W2,
                         ushort_t* __restrict__ n2hWT_h, ushort_t* __restrict__ n2hWT_l,
                         ushort_t* __restrict__ h2nW_h, ushort_t* __restrict__ h2nW_l,
                         float* __restrict__ W1T, float* __restrict__ W2T) {
    __shared__ float tile[32][33];
    int id = blockIdx.x;
    if (id < 2048) {
        int b = id >> 5, r = id & 31;
        int z = r >> 2, cb = r & 3;
        int col = cb * 256 + threadIdx.x;
        if (b == 0 && z == 0) {        // seed atomic accumulators (ws re-poisoned every call)
            rowsumS[col] = 0.f;
            bias_h[col] = n2h_b[col];
        }
        float s = 0.f;
        #pragma unroll 4
        for (int t = z * 32; t < z * 32 + 32; ++t) {
            size_t o = ((size_t)b * Tt + t) * H + col;
            float v = h_time[o];
            s += v;
            ht_bf16[o] = f2bf(v);
        }
        hg_part[(size_t)(b * 8 + z) * H + col] = s;
        return;
    }
    int tx = threadIdx.x & 31, ty = threadIdx.x >> 5;
    if (id < 3072) {            // n2h_W transpose + split
        int t = id - 2048;
        int i0 = (t >> 5) * 32, j0 = (t & 31) * 32;
        #pragma unroll
        for (int q = 0; q < 4; ++q)
            tile[ty + 8 * q][tx] = n2h_W[(size_t)(i0 + ty + 8 * q) * H + j0 + tx];
        __syncthreads();
        #pragma unroll
        for (int q = 0; q < 4; ++q) {
            float v = tile[tx][ty + 8 * q];
            size_t o = (size_t)(j0 + ty + 8 * q) * Nn + i0 + tx;
            ushort_t hh = f2bf(v);
            n2hWT_h[o] = hh;
            n2hWT_l[o] = f2bf(v - bf2f(hh));
        }
    } else if (id < 4096) {     // h2n_W flat split
        size_t idx = (size_t)(id - 3072) * 1024 + threadIdx.x * 4;
        float4 v = *(const float4*)&h2n_W[idx];
        float c[4] = {v.x, v.y, v.z, v.w};
        union { ushort_t u[4]; uint2 w; } ph, pl;
        #pragma unroll
        for (int q = 0; q < 4; ++q) {
            ph.u[q] = f2bf(c[q]);
            pl.u[q] = f2bf(c[q] - bf2f(ph.u[q]));
        }
        *(uint2*)&h2nW_h[idx] = ph.w;
        *(uint2*)&h2nW_l[idx] = pl.w;
    } else if (id < 4608) {     // W1T (W1 is 1024x512)
        int t = id - 4096;
        int i0 = (t >> 4) * 32, j0 = (t & 15) * 32;
        #pragma unroll
        for (int q = 0; q < 4; ++q)
            tile[ty + 8 * q][tx] = W1[(size_t)(i0 + ty + 8 * q) * 512 + j0 + tx];
        __syncthreads();
        #pragma unroll
        for (int q = 0; q < 4; ++q)
            W1T[(size_t)(j0 + ty + 8 * q) * 1024 + i0 + tx] = tile[tx][ty + 8 * q];
    } else {                    // W2T (W2 is 512x1024)
        int t = id - 4608;
        int i0 = (t >> 5) * 32, j0 = (t & 31) * 32;
        #pragma unroll
        for (int q = 0; q < 4; ++q)
            tile[ty + 8 * q][tx] = W2[(size_t)(i0 + ty + 8 * q) * 1024 + j0 + tx];
        __syncthreads();
        #pragma unroll
        for (int q = 0; q < 4; ++q)
            W2T[(size_t)(j0 + ty + 8 * q) * 512 + i0 + tx] = tile[tx][ty + 8 * q];
    }
}

// ---------------- stage 2: h_gate + h_mean from partials.  grid 260 x 256 ----------------
__global__ void k_stage2(const float* __restrict__ hg_part, float* __restrict__ h_gate,
                         float* __restrict__ h_mean) {
    int id = blockIdx.x;
    if (id < 256) {
        int b = id >> 2, cb = id & 3;
        int col = cb * 256 + threadIdx.x;
        float s = 0.f;
        #pragma unroll
        for (int z = 0; z < 8; ++z) s += hg_part[(size_t)(b * 8 + z) * H + col];
        h_gate[b * H + col] = s * (1.0f / Tt);
    } else {
        int h = (id - 256) * 256 + threadIdx.x;
        float s = 0.f;
        for (int r = 0; r < 512; ++r) s += hg_part[(size_t)r * H + h];
        h_mean[h] = s * (1.0f / (Bb * Tt));
    }
}

// ---------------- stage 3: E_cur bf16 + MLP layer 1.  grid 9216 x 256 --------------------
__global__ __launch_bounds__(256) void k_stage3(
    const float* __restrict__ E_dyn, const float* __restrict__ h_mean,
    ushort_t* __restrict__ E_b,
    const float* __restrict__ h_gate, const float* __restrict__ W1T,
    const float* __restrict__ b1, float* __restrict__ hid) {
    if (blockIdx.x < 1024) {   // E_b[n,:] = bf16(normalize(E_dyn[n,:] + h_mean))
        int n = blockIdx.x;
        float e[4]; float ss = 0.f;
        #pragma unroll
        for (int q = 0; q < 4; ++q) {
            int h = threadIdx.x + 256 * q;
            e[q] = E_dyn[(size_t)n * H + h] + h_mean[h];
            ss += e[q] * e[q];
        }
        float tot = block_reduce_sum_256(ss);
        float scale = 1.0f / fmaxf(sqrtf(tot), 1e-12f);
        #pragma unroll
        for (int q = 0; q < 4; ++q) {
            int h = threadIdx.x + 256 * q;
            E_b[(size_t)n * H + h] = f2bf(e[q] * scale);
        }
        return;
    }
    // hid[b][j] = gelu(dot(h_gate[b,:], W1T[j,:]) + b1[j]); wave per output
    int gid = (blockIdx.x - 1024) * 4 + (threadIdx.x >> 6);
    int lane = threadIdx.x & 63;
    int b = gid >> 9, j = gid & 511;
    const float* xr = h_gate + b * H;
    const float* wr = W1T + (size_t)j * H;
    float s = 0.f;
    #pragma unroll
    for (int it = 0; it < 4; ++it) {
        int k = it * 256 + lane * 4;
        float4 x4 = *(const float4*)&xr[k];
        float4 w4 = *(const float4*)&wr[k];
        s += x4.x * w4.x + x4.y * w4.y + x4.z * w4.z + x4.w * w4.w;
    }
    #pragma unroll
    for (int off = 32; off > 0; off >>= 1) s += __shfl_down(s, off, 64);
    if (lane == 0) {
        float a = s + b1[j];
        hid[b * 512 + j] = 0.5f * a * (1.0f + erff(a * 0.70710678118654752f));
    }
}

// ---------------- 64x64-tile MFMA GEMM body, BK=64 ---------------------------------------
// C_raw = A@Bt^T (PASSES=1) or Ah@Bh^T + Ah@Bl^T + Al@Bh^T (PASSES=3).
// EPI 1: relu -> O1 bf16 + atomicAdd row-sums into fout.      (S = relu(E E^T))
// EPI 2: hi/lo bf16 -> O1,O2 + atomicAdd dot(row,fvec)->fout. (C1T + fused bias_h gemv)
// EPI 3: bf16 -> O1.                                          (C2t)
template <int PASSES, int EPI>
__device__ __forceinline__ void gemm64_body(
    int bx, int by,
    const ushort_t* __restrict__ Ah, const ushort_t* __restrict__ Al,
    const ushort_t* __restrict__ Bh, const ushort_t* __restrict__ Bl,
    ushort_t* __restrict__ O1, ushort_t* __restrict__ O2,
    float* __restrict__ fout, const float* __restrict__ fvec,
    int M, int N, int K) {
    constexpr int NST = (PASSES == 3) ? 4 : 2;
    __shared__ ushort_t sStage[NST * 64 * 64];   // BK=64: 8 KB per array
    ushort_t* sAh = sStage;
    ushort_t* sBh = sStage + 64 * 64;
    ushort_t* sAl = sStage + (NST == 4 ? 2 * 64 * 64 : 0);
    ushort_t* sBl = sStage + (NST == 4 ? 3 * 64 * 64 : 0);
    const int tid = threadIdx.x, wave = tid >> 6, lane = tid & 63;
    const int quad = lane >> 4, l16 = lane & 15;
    const int m0 = by * 64, n0 = bx * 64;
    const int wm = (wave >> 1) * 32, wn = (wave & 1) * 32;

    f32x4 acc[2][2];
    #pragma unroll
    for (int i = 0; i < 2; ++i)
        #pragma unroll
        for (int j = 0; j < 2; ++j)
            acc[i][j] = (f32x4){0.f, 0.f, 0.f, 0.f};

    for (int k0 = 0; k0 < K; k0 += 64) {
        __syncthreads();
        #pragma unroll
        for (int inst = 0; inst < 2; ++inst) {
            const int cbase = (wave * 2 + inst) * 64;
            const int c = cbase + lane;
            const int row = c >> 3, q = c & 7;
            const size_t offA = (size_t)(m0 + row) * K + k0 + q * 8;
            const size_t offB = (size_t)(n0 + row) * K + k0 + q * 8;
            __builtin_amdgcn_global_load_lds(
                (const __attribute__((address_space(1))) unsigned int*)(Ah + offA),
                (__attribute__((address_space(3))) unsigned int*)&sAh[cbase * 8], 16, 0, 0);
            __builtin_amdgcn_global_load_lds(
                (const __attribute__((address_space(1))) unsigned int*)(Bh + offB),
                (__attribute__((address_space(3))) unsigned int*)&sBh[cbase * 8], 16, 0, 0);
            if constexpr (PASSES == 3) {
                __builtin_amdgcn_global_load_lds(
                    (const __attribute__((address_space(1))) unsigned int*)(Al + offA),
                    (__attribute__((address_space(3))) unsigned int*)&sAl[cbase * 8], 16, 0, 0);
                __builtin_amdgcn_global_load_lds(
                    (const __attribute__((address_space(1))) unsigned int*)(Bl + offB),
                    (__attribute__((address_space(3))) unsigned int*)&sBl[cbase * 8], 16, 0, 0);
            }
        }
        __syncthreads();
        #pragma unroll
        for (int half = 0; half < 2; ++half) {
            bf16x8 fah[2], fbh[2];
            bf16x8 fal[PASSES == 3 ? 2 : 1], fbl[PASSES == 3 ? 2 : 1];
            #pragma unroll
            for (int i = 0; i < 2; ++i) {
                const int ko = half * 32 + quad * 8;
                fah[i] = *(const bf16x8*)&sAh[(wm + i * 16 + l16) * 64 + ko];
                fbh[i] = *(const bf16x8*)&sBh[(wn + i * 16 + l16) * 64 + ko];
                if constexpr (PASSES == 3) {
                    fal[i] = *(const bf16x8*)&sAl[(wm + i * 16 + l16) * 64 + ko];
                    fbl[i] = *(const bf16x8*)&sBl[(wn + i * 16 + l16) * 64 + ko];
                }
            }
            #pragma unroll
            for (int i = 0; i < 2; ++i)
                #pragma unroll
                for (int j = 0; j < 2; ++j) {
                    acc[i][j] = __builtin_amdgcn_mfma_f32_16x16x32_bf16(fah[i], fbh[j], acc[i][j], 0, 0, 0);
                    if constexpr (PASSES == 3) {
                        acc[i][j] = __builtin_amdgcn_mfma_f32_16x16x32_bf16(fah[i], fbl[j], acc[i][j], 0, 0, 0);
                        acc[i][j] = __builtin_amdgcn_mfma_f32_16x16x32_bf16(fal[i], fbh[j], acc[i][j], 0, 0, 0);
                    }
                }
        }
    }

    // direct-from-register epilogue (outputs small/L2-resident; no LDS round-trip)
    float fv[2];
    if constexpr (EPI == 2) {
        #pragma unroll
        for (int j = 0; j < 2; ++j) fv[j] = fvec[n0 + wn + j * 16 + l16];
    }
    #pragma unroll
    for (int i = 0; i < 2; ++i)
        #pragma unroll
        for (int r = 0; r < 4; ++r) {
            const int m = m0 + wm + i * 16 + quad * 4 + r;
            float rowacc = 0.f;
            #pragma unroll
            for (int j = 0; j < 2; ++j) {
                const size_t o = (size_t)m * N + n0 + wn + j * 16 + l16;
                float v = acc[i][j][r];
                if constexpr (EPI == 1) {
                    v = fmaxf(v, 0.f);
                    O1[o] = f2bf(v);
                    rowacc += v;
                } else if constexpr (EPI == 2) {
                    ushort_t hh = f2bf(v);
                    O1[o] = hh;
                    O2[o] = f2bf(v - bf2f(hh));
                    rowacc += v * fv[j];
                } else {
                    O1[o] = f2bf(v);
                }
            }
            if constexpr (EPI == 1 || EPI == 2) {
                rowacc += __shfl_xor(rowacc, 1);
                rowacc += __shfl_xor(rowacc, 2);
                rowacc += __shfl_xor(rowacc, 4);
                rowacc += __shfl_xor(rowacc, 8);
                if (l16 == 0) atomicAdd(&fout[m], rowacc);
            }
        }
}

// ---------------- stage 4: MLP layer 2 (gmean) + S-GEMM.  grid 512 x 256 -----------------
__global__ __launch_bounds__(256) void k_stage4(
    const float* __restrict__ hid, const float* __restrict__ W2T,
    const float* __restrict__ b2, float* __restrict__ gmean,
    const ushort_t* __restrict__ E_b, ushort_t* __restrict__ Sb,
    float* __restrict__ rowsumS) {
    if (blockIdx.x < 256) {
        int n = blockIdx.x * 4 + (threadIdx.x >> 6);
        int lane = threadIdx.x & 63;
        const float* wr = W2T + (size_t)n * 512;
        float4 w0 = *(const float4*)&wr[lane * 4];
        float4 w1 = *(const float4*)&wr[256 + lane * 4];
        float bb = b2[n];
        float acc = 0.f;
        for (int b = 0; b < Bb; ++b) {
            const float* xr = hid + b * 512;
            float4 x0 = *(const float4*)&xr[lane * 4];
            float4 x1 = *(const float4*)&xr[256 + lane * 4];
            float s = x0.x * w0.x + x0.y * w0.y + x0.z * w0.z + x0.w * w0.w
                    + x1.x * w1.x + x1.y * w1.y + x1.z * w1.z + x1.w * w1.w;
            #pragma unroll
            for (int off = 32; off > 0; off >>= 1) s += __shfl_down(s, off, 64);
            if (lane == 0) acc += 1.0f / (1.0f + expf(-(s + bb)));
        }
        if (lane == 0) gmean[n] = acc * (1.0f / Bb);
        return;
    }
    int t = blockIdx.x - 256;
    gemm64_body<1, 1>(t & 15, t >> 4, E_b, nullptr, E_b, nullptr,
                      Sb, nullptr, rowsumS, nullptr, Nn, Nn, H);
}

// ---------------- A_mix transposed + hi/lo split.  grid(32,32) x 256 ---------------------
__global__ void k_amixT(const ushort_t* __restrict__ Sb, const float* __restrict__ A_p,
                        const float* __restrict__ rowsumS, const float* __restrict__ gmean,
                        const float* __restrict__ alpha_raw,
                        ushort_t* __restrict__ Th, ushort_t* __restrict__ Tl) {
    __shared__ float tile[32][33];
    int i0 = blockIdx.y * 32, j0 = blockIdx.x * 32;
    int tx = threadIdx.x & 31, ty = threadIdx.x >> 5;
    float alpha = 1.0f / (1.0f + expf(-alpha_raw[0]));
    #pragma unroll
    for (int q = 0; q < 4; ++q) {
        int i = i0 + ty + 8 * q, j = j0 + tx;
        size_t idx = (size_t)i * Nn + j;
        float s = bf2f(Sb[idx]);
        float ad = 0.5f * s * (1.0f / (rowsumS[i] + 1e-6f) + 1.0f / (rowsumS[j] + 1e-6f));
        tile[ty + 8 * q][tx] = gmean[i] * fmaf(alpha, A_p[idx], (1.0f - alpha) * ad);
    }
    __syncthreads();
    #pragma unroll
    for (int q = 0; q < 4; ++q) {
        float v = tile[tx][ty + 8 * q];
        size_t o = (size_t)(j0 + ty + 8 * q) * Nn + i0 + tx;
        ushort_t hh = f2bf(v);
        Th[o] = hh;
        Tl[o] = f2bf(v - bf2f(hh));
    }
}

// chain GEMM wrappers.  grid 256 x 256
__global__ __launch_bounds__(256) void k_c1t(
    const ushort_t* __restrict__ Ah, const ushort_t* __restrict__ Al,
    const ushort_t* __restrict__ Bh, const ushort_t* __restrict__ Bl,
    ushort_t* __restrict__ O1, ushort_t* __restrict__ O2,
    float* __restrict__ fout, const float* __restrict__ fvec) {
    gemm64_body<3, 2>(blockIdx.x & 15, blockIdx.x >> 4, Ah, Al, Bh, Bl, O1, O2, fout, fvec,
                      Nn, Nn, Nn);
}
__global__ __launch_bounds__(256) void k_c2t(
    const ushort_t* __restrict__ Ah, const ushort_t* __restrict__ Al,
    const ushort_t* __restrict__ Bh, const ushort_t* __restrict__ Bl,
    ushort_t* __restrict__ O1) {
    gemm64_body<3, 3>(blockIdx.x & 15, blockIdx.x >> 4, Ah, Al, Bh, Bl, O1, nullptr,
                      nullptr, nullptr, Nn, Nn, Nn);
}

// ---------------- 128x128 MFMA GEMM, BK=64, fused y-epilogue.  1D grid 1024 --------------
// y[m][n] = (ht @ C2t^T)[m][n] + bias[n] + SC*bf16(ht[m][n]), fp32 -> fout.
__global__ __launch_bounds__(256) void gemm_big(
    const ushort_t* __restrict__ A, const ushort_t* __restrict__ Bt,
    float* __restrict__ fout, const float* __restrict__ fvec,
    int M, int N, int K) {
    __shared__ ushort_t sStage[2 * 128 * 64];   // 32 KB (BK=64)
    ushort_t* sAh = sStage;
    ushort_t* sBh = sStage + 128 * 64;

    const int tid = threadIdx.x;
    const int wave = tid >> 6, lane = tid & 63;
    const int quad = lane >> 4, l16 = lane & 15;
    int bx = blockIdx.x, g = bx & 7, s = bx >> 3;   // XCD-aware: A-panel locality per XCD
    const int m0 = (g * 16 + (s >> 3)) * 128;
    const int n0 = (s & 7) * 128;
    const int wm = (wave >> 1) * 64, wn = (wave & 1) * 64;

    f32x4 acc[4][4];
    #pragma unroll
    for (int i = 0; i < 4; ++i)
        #pragma unroll
        for (int j = 0; j < 4; ++j)
            acc[i][j] = (f32x4){0.f, 0.f, 0.f, 0.f};

    for (int k0 = 0; k0 < K; k0 += 64) {
        __syncthreads();
        #pragma unroll
        for (int inst = 0; inst < 4; ++inst) {
            const int cbase = (wave * 4 + inst) * 64;
            const int c = cbase + lane;
            const int row = c >> 3, q = c & 7;
            const size_t offA = (size_t)(m0 + row) * K + k0 + q * 8;
            const size_t offB = (size_t)(n0 + row) * K + k0 + q * 8;
            __builtin_amdgcn_global_load_lds(
                (const __attribute__((address_space(1))) unsigned int*)(A + offA),
                (__attribute__((address_space(3))) unsigned int*)&sAh[cbase * 8], 16, 0, 0);
            __builtin_amdgcn_global_load_lds(
                (const __attribute__((address_space(1))) unsigned int*)(Bt + offB),
                (__attribute__((address_space(3))) unsigned int*)&sBh[cbase * 8], 16, 0, 0);
        }
        __syncthreads();
        #pragma unroll
        for (int half = 0; half < 2; ++half) {
            bf16x8 fah[4], fbh[4];
            #pragma unroll
            for (int i = 0; i < 4; ++i) {
                const int ko = half * 32 + quad * 8;
                fah[i] = *(const bf16x8*)&sAh[(wm + i * 16 + l16) * 64 + ko];
                fbh[i] = *(const bf16x8*)&sBh[(wn + i * 16 + l16) * 64 + ko];
            }
            #pragma unroll
            for (int i = 0; i < 4; ++i)
                #pragma unroll
                for (int j = 0; j < 4; ++j)
                    acc[i][j] = __builtin_amdgcn_mfma_f32_16x16x32_bf16(fah[i], fbh[j], acc[i][j], 0, 0, 0);
        }
    }
    __syncthreads();   // staging dead; epilogue overlays it

    // Epilogue: per-wave LDS transpose in the dead staging buffer -> coalesced float4 IO.
    // __syncthreads() between write/read phases is REQUIRED (type-punned LDS; R4 lesson).
    float* EsW = (float*)sStage + wave * (16 * 64);
    const float SC = 1.0009765622f;   // 1 + tanh(1/1024): attention branch is this constant

    #pragma unroll
    for (int i = 0; i < 4; ++i) {
        #pragma unroll
        for (int j = 0; j < 4; ++j)
            #pragma unroll
            for (int r = 0; r < 4; ++r)
                EsW[(quad * 4 + r) * 64 + j * 16 + l16] = acc[i][j][r];
        __syncthreads();
        #pragma unroll
        for (int it = 0; it < 4; ++it) {
            const int idx = it * 64 + lane;
            const int row = idx >> 4, f4 = idx & 15;
            const int m = m0 + wm + i * 16 + row;
            const int coln = n0 + wn + f4 * 4;
            float4 v = *(const float4*)&EsW[row * 64 + f4 * 4];
            float4 b4 = *(const float4*)&fvec[coln];
            ushort4 h4 = *(const ushort4*)&A[(size_t)m * N + coln];
            float4 y;
            y.x = v.x + b4.x + SC * bf2f(h4.x);
            y.y = v.y + b4.y + SC * bf2f(h4.y);
            y.z = v.z + b4.z + SC * bf2f(h4.z);
            y.w = v.w + b4.w + SC * bf2f(h4.w);
            *(float4*)&fout[(size_t)m * N + coln] = y;
        }
        __syncthreads();
    }
}

// ---------------- final LayerNorm, wave-per-row, in-place.  grid 4096 x 256 --------------
__global__ __launch_bounds__(256) void k_final_ln(const float* __restrict__ ln_w,
                                                  const float* __restrict__ ln_b,
                                                  float* __restrict__ out) {
    int wave = threadIdx.x >> 6, lane = threadIdx.x & 63;
    size_t row = (size_t)blockIdx.x * 4 + wave;
    float4 v[4];
    float s = 0.f;
    #pragma unroll
    for (int q = 0; q < 4; ++q) {
        v[q] = *(const float4*)&out[row * H + q * 256 + lane * 4];
        s += v[q].x + v[q].y + v[q].z + v[q].w;
    }
    #pragma unroll
    for (int off = 1; off < 64; off <<= 1) s += __shfl_xor(s, off, 64);
    float mu = s * (1.0f / H);
    float ss = 0.f;
    #pragma unroll
    for (int q = 0; q < 4; ++q) {
        v[q].x -= mu; v[q].y -= mu; v[q].z -= mu; v[q].w -= mu;
        ss += v[q].x * v[q].x + v[q].y * v[q].y + v[q].z * v[q].z + v[q].w * v[q].w;
    }
    #pragma unroll
    for (int off = 1; off < 64; off <<= 1) ss += __shfl_xor(ss, off, 64);
    float rstd = rsqrtf(ss * (1.0f / H) + 1e-5f);
    #pragma unroll
    for (int q = 0; q < 4; ++q) {
        int k = q * 256 + lane * 4;
        float4 w4 = *(const float4*)&ln_w[k];
        float4 b4 = *(const float4*)&ln_b[k];
        float4 o;
        o.x = fmaf(v[q].x * rstd, w4.x, b4.x);
        o.y = fmaf(v[q].y * rstd, w4.y, b4.y);
        o.z = fmaf(v[q].z * rstd, w4.z, b4.z);
        o.w = fmaf(v[q].w * rstd, w4.w, b4.w);
        *(float4*)&out[row * H + k] = o;
    }
}

// ---------------- launch ----------------

extern "C" void kernel_launch(void* const* d_in, const int* in_sizes, int n_in,
                              void* d_out, int out_size, void* d_ws, size_t ws_size,
                              hipStream_t stream) {
    const float* h_time    = (const float*)d_in[0];
    const float* A_p       = (const float*)d_in[1];
    const float* E_dyn     = (const float*)d_in[2];
    const float* alpha_raw = (const float*)d_in[3];
    // d_in[4] = tau_raw: unused (softmax over axis 0 => node_attn.mean(0) == 1/N exactly)
    const float* gW1   = (const float*)d_in[5];
    const float* gb1   = (const float*)d_in[6];
    const float* gW2   = (const float*)d_in[7];
    const float* gb2   = (const float*)d_in[8];
    const float* h2n_W = (const float*)d_in[9];
    const float* h2n_b = (const float*)d_in[10];
    const float* n2h_W = (const float*)d_in[11];
    const float* n2h_b = (const float*)d_in[12];
    const float* ln_w  = (const float*)d_in[13];
    const float* ln_b  = (const float*)d_in[14];
    float* out = (float*)d_out;

    float* ws = (float*)d_ws;
    float* h_gate  = ws;  ws += Bb * H;
    float* h_mean  = ws;  ws += H;
    float* rowsumS = ws;  ws += Nn;
    float* bias_h  = ws;  ws += H;
    float* hid     = ws;  ws += Bb * 512;
    float* gmean   = ws;  ws += Nn;
    float* W1T     = ws;  ws += 512 * H;
    float* W2T     = ws;  ws += H * 512;
    float* hg_part = ws;  ws += 512 * H;       // 8 t-chunks x 64 b
    ws += 256;   // alignment pad
    ushort_t* E_b     = (ushort_t*)ws;  ws += (Nn * H) / 2;
    ushort_t* Sb      = (ushort_t*)ws;  ws += (Nn * Nn) / 2;
    ushort_t* AmixT_h = (ushort_t*)ws;  ws += (Nn * Nn) / 2;
    ushort_t* AmixT_l = (ushort_t*)ws;  ws += (Nn * Nn) / 2;
    ushort_t* n2hWT_h = (ushort_t*)ws;  ws += (Nn * H) / 2;
    ushort_t* n2hWT_l = (ushort_t*)ws;  ws += (Nn * H) / 2;
    ushort_t* h2nW_h  = (ushort_t*)ws;  ws += (H * Nn) / 2;
    ushort_t* h2nW_l  = (ushort_t*)ws;  ws += (H * Nn) / 2;
    ushort_t* C1Th    = (ushort_t*)ws;  ws += (H * Nn) / 2;
    ushort_t* C1Tl    = (ushort_t*)ws;  ws += (H * Nn) / 2;
    ushort_t* C2t     = (ushort_t*)ws;  ws += (H * H) / 2;
    ushort_t* ht      = (ushort_t*)ws;  ws += ((size_t)BT * H) / 2;

    // 1: hgate partials (x8 t-split) + bf16 ht + seeds + all weight prep
    k_stage1<<<5120, 256, 0, stream>>>(h_time, hg_part, ht, n2h_b, rowsumS, bias_h,
                                       n2h_W, h2n_W, gW1, gW2,
                                       n2hWT_h, n2hWT_l, h2nW_h, h2nW_l, W1T, W2T);
    // 2: h_gate + h_mean
    k_stage2<<<260, 256, 0, stream>>>(hg_part, h_gate, h_mean);
    // 3: E_cur bf16 + MLP layer 1
    k_stage3<<<9216, 256, 0, stream>>>(E_dyn, h_mean, E_b, h_gate, W1T, gb1, hid);
    // 4: MLP layer 2 (gmean) + S = relu(E E^T) bf16 + row sums
    k_stage4<<<512, 256, 0, stream>>>(hid, W2T, gb2, gmean, E_b, Sb, rowsumS);
    // 5: A_mix^T hi/lo
    k_amixT<<<dim3(32, 32), 256, 0, stream>>>(Sb, A_p, rowsumS, gmean, alpha_raw, AmixT_h, AmixT_l);
    // 6: C1T = n2h_W^T @ A_mix^T (3-pass) -> hi/lo + fused bias_h gemv
    k_c1t<<<256, 256, 0, stream>>>(n2hWT_h, n2hWT_l, AmixT_h, AmixT_l, C1Th, C1Tl, bias_h, h2n_b);
    // 7: C2t = C1T @ h2n_W (3-pass) -> bf16   (= C2^T, the big GEMM's B operand)
    k_c2t<<<256, 256, 0, stream>>>(C1Th, C1Tl, h2nW_h, h2nW_l, C2t);
    // 8: y = ht @ C2t^T + bias_h + SC*ht -> d_out fp32 (fused epilogue)
    gemm_big<<<1024, 256, 0, stream>>>(ht, C2t, out, bias_h, BT, H, H);
    // 9: LayerNorm in place (wave per row)
    k_final_ln<<<4096, 256, 0, stream>>>(ln_w, ln_b, out);
}